// Round 9
// baseline (4538.891 us; speedup 1.0000x reference)
//
#include <hip/hip_runtime.h>

// WholeBrainFastDMF: N=360, B=8, T=7500 neural steps (750 hemo).
// One persistent block (1 CU) per batch, 8 waves / 512 threads.
// Matvec on the MFMA pipe (v_mfma_i32_16x16x64_i8), E broadcast across all 16
// B-columns -> lane (g<<4|c) holds y[16T+4g+reg] in its own acc regs, zero
// shuffle extraction. Wave w owns rows [48w,48w+48) as 3 row-tiles of 16.
// R9: MFMA chains split 3+3 (halved dep latency, int-exact), hemo update
// hoisted off the critical path (runs at top of next step), relaxed barrier
// (lgkm-only drain, single post-barrier sched fence).

typedef unsigned int u32;
typedef int i32x4 __attribute__((ext_vector_type(4)));

#define NN 360
#define NB 8
#define NT 7500
#define NHEMO 750

#define S_SC 45720.0f            // sc scale: sc*360 in [0,1) -> *127
#define S_E  64.0f               // E scale (E < 1.98)
#define CONN_K 1.0252653e-7f     // 0.3 / (45720*64)   (G*JN = 0.3 folded)

__device__ __forceinline__ float frcp(float x) {
#if __has_builtin(__builtin_amdgcn_rcpf)
  return __builtin_amdgcn_rcpf(x);
#else
  return 1.0f / x;
#endif
}
__device__ __forceinline__ float fexp2(float x) {
#if __has_builtin(__builtin_amdgcn_exp2f)
  return __builtin_amdgcn_exp2f(x);
#else
  return exp2f(x);
#endif
}
__device__ __forceinline__ float flog2(float x) {
#if __has_builtin(__builtin_amdgcn_logf)
  return __builtin_amdgcn_logf(x);
#else
  return log2f(x);
#endif
}

// Workgroup barrier with lgkm-only drain: ds_write made visible, VMEM
// prefetches stay in flight. Single post-barrier fence pins next-step
// ds_reads below the barrier while letting VALU mix freely elsewhere.
__device__ __forceinline__ void lds_barrier() {
  asm volatile("s_waitcnt lgkmcnt(0)" ::: "memory");
  __builtin_amdgcn_s_barrier();
  __builtin_amdgcn_sched_barrier(0);
}

__global__ __launch_bounds__(512, 2) void dmf_kernel(
    const float* __restrict__ state,
    const float* __restrict__ noise_in,
    const float* __restrict__ noise_out,
    const float* __restrict__ sc,
    float* __restrict__ out)
{
  const int b   = blockIdx.x;
  const int tid = threadIdx.x;
  const int w   = tid >> 6;
  const int l   = tid & 63;
  const int g   = l >> 4;        // k-slice group (A/B) AND C row-group
  const int r   = l & 15;        // A row within tile; also C col index c
  // owner decode: lane (g<<4)|c with c<12 owns row 48w + 16*(c>>2) + 4g + (c&3)
  const int t_o = r >> 2;        // owner tile 0..3 (valid < 3)
  const int j_o = r & 3;         // acc register index
  const int R_o = 48*w + 16*t_o + 4*g + j_o;
  const bool upd = (r < 12) && (R_o < NN);
  const int Rn  = upd ? R_o : 0; // safe row for address bases

  __shared__ u32 xq[2][96];      // int8 E, linear 384B each (360 data + 24 zero)

  if (tid < 192) ((u32*)xq)[tid] = 0;   // zero both buffers (pads stay 0)

  // ---- build A-frags: quantize sc rows into MFMA layout; f32 row sums ----
  i32x4 afr[3][6];
  float rs[3];
  #pragma unroll
  for (int t = 0; t < 3; ++t) {
    const int R = 48*w + 16*t + r;
    const bool rv = (R < NN);
    const float* sp = sc + ((size_t)b*NN + (rv ? R : 0))*NN;
    float acc = 0.f;
    #pragma unroll
    for (int kf = 0; kf < 6; ++kf) {
      i32x4 pk;
      #pragma unroll
      for (int d = 0; d < 4; ++d) {
        int packv = 0;
        #pragma unroll
        for (int e = 0; e < 4; ++e) {
          const int k = 64*kf + 16*g + 4*d + e;
          int q = 0;
          if (rv && k < NN) {
            const float x = sp[k];
            acc += x;
            q = (int)rintf(x * S_SC);
          }
          packv |= q << (8*e);
        }
        pk[d] = packv;
      }
      afr[t][kf] = pk;
    }
    rs[t] = acc;
  }
  // full row sums: reduce over the 4 k-slice groups (lanes ^16, ^32)
  #pragma unroll
  for (int t = 0; t < 3; ++t) {
    rs[t] += __shfl_xor(rs[t], 16, 64);
    rs[t] += __shfl_xor(rs[t], 32, 64);
  }
  // owner pulls rowsum of in-tile row rho = 4g + j_o (held by lane rho, tile t_o)
  const int rho = 4*g + j_o;
  const int qs0 = __builtin_amdgcn_ds_bpermute(4*rho, __float_as_int(rs[0]));
  const int qs1 = __builtin_amdgcn_ds_bpermute(4*rho, __float_as_int(rs[1]));
  const int qs2 = __builtin_amdgcn_ds_bpermute(4*rho, __float_as_int(rs[2]));
  const float rsum = __int_as_float((t_o == 0) ? qs0 : ((t_o == 1) ? qs1 : qs2));

  // ---- owner init: Ji, state, publish E into buffer 0, noise t=0,1 ----
  float E=0.f, I=0.f, ss=0.f, ff=0.f, vv=0.f, qq=0.f, Ji=0.f;
  const float* np = noise_in + (size_t)Rn * NT * 2 * NB + b;
  float n0E=0.f, n0I=0.f, n1E=0.f, n1I=0.f;
  __syncthreads();   // xq zeroing complete
  if (upd) {
    Ji = 1.0f + 1.5f * rsum;
    const float* st = state + (size_t)R_o * 6 * NB + b;
    E  = st[0];
    I  = st[NB];
    ss = st[2*NB];
    ff = st[3*NB];
    vv = st[4*NB];
    qq = st[5*NB];
    int qv = (int)rintf(E * S_E);
    qv = qv > 127 ? 127 : qv;
    ((char*)&xq[0][0])[R_o] = (char)qv;
    n0E = np[0];      n0I = np[NB];       // t = 0
    n1E = np[2*NB];   n1I = np[3*NB];     // t = 1
  }
  np += 4*NB;        // points at t = 2
  __syncthreads();   // buffer 0 visible

  const u32* xb0 = &xq[0][4*g];
  const u32* xb1 = &xq[1][4*g];
  char* pb0 = (char*)&xq[0][0] + Rn;
  char* pb1 = (char*)&xq[1][0] + Rn;
  const bool w7 = (w == 7);      // wave 7 tile 2 = rows 368..383, all zero

  // hemodynamic update: depends only on (E,ss,ff,vv,qq) -> can run any time
  // between the neural step it follows and the next hemo step.
  auto hemo_update = [&]() {
    if (upd) {
      const float l2v  = flog2(vv);
      const float v_ia = fexp2(3.125f * l2v);            // v**(1/0.32)
      const float v_r  = fexp2(2.125f * l2v);            // v**(1/0.32-1)
      const float ds_  = E - 1.53846153846f*ss - 2.43902439024f*(ff - 1.f);
      const float df_  = ss;
      const float dv_  = (ff - v_ia) * 1.02040816327f;
      const float pw   = fexp2(-0.59946207f * frcp(ff)); // (1-RHO)**(1/f)
      const float dq_  = (ff*2.94117647059f*(1.f - pw) - qq*v_r) * 1.02040816327f;
      ss += 1e-3f*ds_;
      ff += 1e-3f*df_;
      vv += 1e-3f*dv_;
      qq += 1e-3f*dq_;
    }
  };

  // one neural step: read B-frags from xb, write E byte at pbn.
  // HEMO: run the (deferred) hemo update inside this step's latency window.
  auto body = [&](const u32* xb, char* pbn, bool PF, bool HEMO) {
    // 1) B-frags (6 x ds_read_b128, broadcast within each 16-lane group)
    i32x4 bf[6];
    #pragma unroll
    for (int kf = 0; kf < 6; ++kf) bf[kf] = *(const i32x4*)(xb + 16*kf);

    // 2) noise prefetch t+2 (stays in flight across lgkm-only barriers)
    float n2E = n1E, n2I = n1I;
    if (PF) {
      if (upd) { n2E = np[0]; n2I = np[NB]; }
      np += 2*NB;
    }

    // 3) deferred hemo: overlaps the ds_read/MFMA latency window
    if (HEMO) hemo_update();

    // 4) matvec on the MFMA pipe: 3 row-tiles, each split 3+3 (int-exact)
    const i32x4 Z = {0,0,0,0};
    i32x4 a0a = Z, a0b = Z, a1a = Z, a1b = Z, a2a = Z, a2b = Z;
    #pragma unroll
    for (int kf = 0; kf < 3; ++kf) {
      a0a = __builtin_amdgcn_mfma_i32_16x16x64_i8(afr[0][kf],   bf[kf],   a0a, 0, 0, 0);
      a0b = __builtin_amdgcn_mfma_i32_16x16x64_i8(afr[0][kf+3], bf[kf+3], a0b, 0, 0, 0);
    }
    #pragma unroll
    for (int kf = 0; kf < 3; ++kf) {
      a1a = __builtin_amdgcn_mfma_i32_16x16x64_i8(afr[1][kf],   bf[kf],   a1a, 0, 0, 0);
      a1b = __builtin_amdgcn_mfma_i32_16x16x64_i8(afr[1][kf+3], bf[kf+3], a1b, 0, 0, 0);
    }
    if (!w7) {
      #pragma unroll
      for (int kf = 0; kf < 3; ++kf) {
        a2a = __builtin_amdgcn_mfma_i32_16x16x64_i8(afr[2][kf],   bf[kf],   a2a, 0, 0, 0);
        a2b = __builtin_amdgcn_mfma_i32_16x16x64_i8(afr[2][kf+3], bf[kf+3], a2b, 0, 0, 0);
      }
    }
    const i32x4 ac0 = a0a + a0b;
    const i32x4 ac1 = a1a + a1b;
    const i32x4 ac2 = a2a + a2b;

    // 5) conn: every B-column equals y, so acc reg j_o of tile t_o IS y[R_o]
    const i32x4 at = (t_o == 0) ? ac0 : ((t_o == 1) ? ac1 : ac2);
    const int ci = (j_o == 0) ? at.x : ((j_o == 1) ? at.y : ((j_o == 2) ? at.z : at.w));

    if (upd) {
      const float cs = (float)ci * CONN_K;                 // G*JN*conn
      float I_E = fmaxf(0.382f + 0.21f*E + cs - Ji*I, 0.f);
      float I_I = fmaxf(0.2674f + 0.15f*E - I, 0.f);
      const float xE  = 310.f*I_E - 125.f;
      const float R_E = xE * frcp(1.f - fexp2(-0.23083120f*xE) + 1e-8f);
      const float xI  = 615.f*I_I - 177.f;
      const float R_I = xI * frcp(1.f - fexp2(-0.12551447f*xI) + 1e-8f);
      const float dE = -E*0.01f + (1.f - E)*0.000641f*R_E;
      const float dI = -I*0.1f  + 0.001f*R_I;
      E = fmaxf(E + 0.1f*dE + 0.00158113883f*n0E, 0.f);
      I = fmaxf(I + 0.1f*dI + 0.00158113883f*n0I, 0.f);
      int qv = (int)(E * S_E + 0.5f);
      qv = qv > 127 ? 127 : qv;
      *pbn = (char)qv;
    }
    n0E = n1E; n0I = n1I;
    n1E = n2E; n1I = n2I;
    lds_barrier();   // next buffer complete; vmcnt loads stay in flight
  };

  for (int hs = 0; hs < NHEMO; ++hs) {
    const bool last = (hs == NHEMO - 1);
    // deferred hemo from the previous hs runs inside the first step's window
    body(xb0, pb1, true, hs != 0);
    body(xb1, pb0, true, false);
    body(xb0, pb1, true, false);
    body(xb1, pb0, true, false);
    body(xb0, pb1, true, false);
    body(xb1, pb0, true, false);
    body(xb0, pb1, true, false);
    body(xb1, pb0, true, false);
    body(xb0, pb1, !last, false);
    body(xb1, pb0, !last, false);
  }
  hemo_update();   // final hs's hemo

  // ---- outputs: next_state (N,6,B) then bold (N,B) ----
  if (upd) {
    float* o = out + (size_t)R_o * 6 * NB + b;
    o[0]    = E;
    o[NB]   = I;
    o[2*NB] = ss;
    o[3*NB] = ff;
    o[4*NB] = vv;
    o[5*NB] = qq;
    out[NN*6*NB + R_o*NB + b] =
        20.f*(2.38f*(1.f - qq) + 2.f*(1.f - qq/vv) + 0.48f*(1.f - vv))
        + noise_out[R_o*NB + b];
  }
}

extern "C" void kernel_launch(void* const* d_in, const int* in_sizes, int n_in,
                              void* d_out, int out_size, void* d_ws, size_t ws_size,
                              hipStream_t stream) {
  const float* state     = (const float*)d_in[0];
  // d_in[1] = delays (unused by the reference simulation)
  const float* noise_in  = (const float*)d_in[2];
  const float* noise_out = (const float*)d_in[3];
  const float* sc        = (const float*)d_in[4];
  float* out = (float*)d_out;
  dmf_kernel<<<NB, 512, 0, stream>>>(state, noise_in, noise_out, sc, out);
}

// Round 10
// 4428.452 us; speedup vs baseline: 1.0249x; 1.0249x over previous
//
#include <hip/hip_runtime.h>

// WholeBrainFastDMF: N=360, B=8, T=7500 neural steps (750 hemo).
// One persistent block (1 CU) per batch, 12 waves / 768 threads (3/SIMD TLP).
// Matvec on the MFMA pipe (v_mfma_i32_16x16x64_i8), E broadcast across all 16
// B-columns -> lane (g<<4|c) holds y[16T+4g+reg] in its own acc regs, zero
// shuffle extraction. Wave w owns rows [32w,32w+32) as 2 row-tiles of 16.
// A-frags: 2 tiles x 6 kfrags x 4 VGPRs = 48. E int8 double-buffered in LDS
// (linear 384B, zero pad 360..383). One lgkm-only barrier per step; 2-step
// noise prefetch; fast rcp/exp2/log2. (Structure otherwise identical to the
// round-8 kernel, which measured 4388 us at 8 waves.)

typedef unsigned int u32;
typedef int i32x4 __attribute__((ext_vector_type(4)));

#define NN 360
#define NB 8
#define NT 7500
#define NHEMO 750

#define S_SC 45720.0f            // sc scale: sc*360 in [0,1) -> *127
#define S_E  64.0f               // E scale (E < 1.98)
#define CONN_K 1.0252653e-7f     // 0.3 / (45720*64)   (G*JN = 0.3 folded)

__device__ __forceinline__ float frcp(float x) {
#if __has_builtin(__builtin_amdgcn_rcpf)
  return __builtin_amdgcn_rcpf(x);
#else
  return 1.0f / x;
#endif
}
__device__ __forceinline__ float fexp2(float x) {
#if __has_builtin(__builtin_amdgcn_exp2f)
  return __builtin_amdgcn_exp2f(x);
#else
  return exp2f(x);
#endif
}
__device__ __forceinline__ float flog2(float x) {
#if __has_builtin(__builtin_amdgcn_logf)
  return __builtin_amdgcn_logf(x);
#else
  return log2f(x);
#endif
}

// Workgroup barrier with lgkm-only drain: ds_write made visible, VMEM
// prefetches stay in flight across the barrier.
__device__ __forceinline__ void lds_barrier() {
  __builtin_amdgcn_sched_barrier(0);
  asm volatile("s_waitcnt lgkmcnt(0)" ::: "memory");
  __builtin_amdgcn_s_barrier();
  asm volatile("" ::: "memory");
  __builtin_amdgcn_sched_barrier(0);
}

__global__ __launch_bounds__(768, 3) void dmf_kernel(
    const float* __restrict__ state,
    const float* __restrict__ noise_in,
    const float* __restrict__ noise_out,
    const float* __restrict__ sc,
    float* __restrict__ out)
{
  const int b   = blockIdx.x;
  const int tid = threadIdx.x;
  const int w   = tid >> 6;      // wave 0..11
  const int l   = tid & 63;
  const int g   = l >> 4;        // k-slice group (A/B) AND C row-group
  const int r   = l & 15;        // A row within tile; also C col index c
  // owner decode: lane (g<<4)|r with r<8 owns row 32w + 16*(r>>2) + 4g + (r&3)
  const int t_o = r >> 2;        // owner tile 0..3 (valid < 2)
  const int j_o = r & 3;         // acc register index
  const int R_o = 32*w + 16*t_o + 4*g + j_o;
  const bool upd = (r < 8) && (R_o < NN);
  const int Rn  = upd ? R_o : 0; // safe row for address bases

  __shared__ u32 xq[2][96];      // int8 E, linear 384B each (360 data + 24 zero)

  if (tid < 192) ((u32*)xq)[tid] = 0;   // zero both buffers (pads stay 0)

  // ---- build A-frags: quantize sc rows into MFMA layout; f32 row sums ----
  // lane supplies row (32w+16t + r), k-bytes 64*kf + 16*g + 0..15
  i32x4 afr[2][6];
  float rs[2];
  #pragma unroll
  for (int t = 0; t < 2; ++t) {
    const int R = 32*w + 16*t + r;
    const bool rv = (R < NN);
    const float* sp = sc + ((size_t)b*NN + (rv ? R : 0))*NN;
    float acc = 0.f;
    #pragma unroll
    for (int kf = 0; kf < 6; ++kf) {
      i32x4 pk;
      #pragma unroll
      for (int d = 0; d < 4; ++d) {
        int packv = 0;
        #pragma unroll
        for (int e = 0; e < 4; ++e) {
          const int k = 64*kf + 16*g + 4*d + e;
          int q = 0;
          if (rv && k < NN) {
            const float x = sp[k];
            acc += x;
            q = (int)rintf(x * S_SC);
          }
          packv |= q << (8*e);
        }
        pk[d] = packv;
      }
      afr[t][kf] = pk;
    }
    rs[t] = acc;
  }
  // full row sums: reduce over the 4 k-slice groups (lanes ^16, ^32)
  #pragma unroll
  for (int t = 0; t < 2; ++t) {
    rs[t] += __shfl_xor(rs[t], 16, 64);
    rs[t] += __shfl_xor(rs[t], 32, 64);
  }
  // owner pulls rowsum of in-tile row rho = 4g + j_o (held by lane rho)
  const int rho = 4*g + j_o;
  const int qs0 = __builtin_amdgcn_ds_bpermute(4*rho, __float_as_int(rs[0]));
  const int qs1 = __builtin_amdgcn_ds_bpermute(4*rho, __float_as_int(rs[1]));
  const float rsum = __int_as_float((t_o == 0) ? qs0 : qs1);

  // ---- owner init: Ji, state, publish E into buffer 0, noise t=0,1 ----
  float E=0.f, I=0.f, ss=0.f, ff=0.f, vv=0.f, qq=0.f, Ji=0.f;
  const float* np = noise_in + (size_t)Rn * NT * 2 * NB + b;
  float n0E=0.f, n0I=0.f, n1E=0.f, n1I=0.f;
  __syncthreads();   // xq zeroing complete
  if (upd) {
    Ji = 1.0f + 1.5f * rsum;
    const float* st = state + (size_t)R_o * 6 * NB + b;
    E  = st[0];
    I  = st[NB];
    ss = st[2*NB];
    ff = st[3*NB];
    vv = st[4*NB];
    qq = st[5*NB];
    int qv = (int)rintf(E * S_E);
    qv = qv > 127 ? 127 : qv;
    ((char*)&xq[0][0])[R_o] = (char)qv;
    n0E = np[0];      n0I = np[NB];       // t = 0
    n1E = np[2*NB];   n1I = np[3*NB];     // t = 1
  }
  np += 4*NB;        // points at t = 2
  __syncthreads();   // buffer 0 visible

  const u32* xb0 = &xq[0][4*g];
  const u32* xb1 = &xq[1][4*g];
  char* pb0 = (char*)&xq[0][0] + Rn;
  char* pb1 = (char*)&xq[1][0] + Rn;
  const bool skip1 = (32*w + 16 >= NN);  // wave 11 tile 1 = rows 368..383, all zero

  // one neural step: read B-frags from xb, write E byte at pbn
  auto body = [&](const u32* xb, char* pbn, bool PF, bool hemo) {
    // 1) B-frags: k-slice per group g (6 x ds_read_b128, broadcast in-group)
    i32x4 bf[6];
    #pragma unroll
    for (int kf = 0; kf < 6; ++kf) bf[kf] = *(const i32x4*)(xb + 16*kf);

    // 2) noise prefetch t+2 (stays in flight across lgkm-only barriers)
    float n2E = n1E, n2I = n1I;
    if (PF) {
      if (upd) { n2E = np[0]; n2I = np[NB]; }
      np += 2*NB;
    }

    // 3) matvec on the MFMA pipe: 2 accumulate chains of 6
    i32x4 ac0 = {0,0,0,0}, ac1 = {0,0,0,0};
    #pragma unroll
    for (int kf = 0; kf < 6; ++kf)
      ac0 = __builtin_amdgcn_mfma_i32_16x16x64_i8(afr[0][kf], bf[kf], ac0, 0, 0, 0);
    if (!skip1) {
      #pragma unroll
      for (int kf = 0; kf < 6; ++kf)
        ac1 = __builtin_amdgcn_mfma_i32_16x16x64_i8(afr[1][kf], bf[kf], ac1, 0, 0, 0);
    }

    // 4) conn: every B-column equals y, so my acc reg j_o of tile t_o IS y[R_o]
    const i32x4 at = (t_o == 0) ? ac0 : ac1;
    const int ci = (j_o == 0) ? at.x : ((j_o == 1) ? at.y : ((j_o == 2) ? at.z : at.w));

    if (upd) {
      const float cs = (float)ci * CONN_K;                 // G*JN*conn
      float I_E = fmaxf(0.382f + 0.21f*E + cs - Ji*I, 0.f);
      float I_I = fmaxf(0.2674f + 0.15f*E - I, 0.f);
      const float xE  = 310.f*I_E - 125.f;
      const float R_E = xE * frcp(1.f - fexp2(-0.23083120f*xE) + 1e-8f);
      const float xI  = 615.f*I_I - 177.f;
      const float R_I = xI * frcp(1.f - fexp2(-0.12551447f*xI) + 1e-8f);
      const float dE = -E*0.01f + (1.f - E)*0.000641f*R_E;
      const float dI = -I*0.1f  + 0.001f*R_I;
      E = fmaxf(E + 0.1f*dE + 0.00158113883f*n0E, 0.f);
      I = fmaxf(I + 0.1f*dI + 0.00158113883f*n0I, 0.f);
      int qv = (int)(E * S_E + 0.5f);
      qv = qv > 127 ? 127 : qv;
      *pbn = (char)qv;
      if (hemo) {
        const float l2v  = flog2(vv);
        const float v_ia = fexp2(3.125f * l2v);            // v**(1/0.32)
        const float v_r  = fexp2(2.125f * l2v);            // v**(1/0.32-1)
        const float ds_  = E - 1.53846153846f*ss - 2.43902439024f*(ff - 1.f);
        const float df_  = ss;
        const float dv_  = (ff - v_ia) * 1.02040816327f;
        const float pw   = fexp2(-0.59946207f * frcp(ff)); // (1-RHO)**(1/f)
        const float dq_  = (ff*2.94117647059f*(1.f - pw) - qq*v_r) * 1.02040816327f;
        ss += 1e-3f*ds_;
        ff += 1e-3f*df_;
        vv += 1e-3f*dv_;
        qq += 1e-3f*dq_;
      }
    }
    n0E = n1E; n0I = n1I;
    n1E = n2E; n1I = n2I;
    lds_barrier();   // next buffer complete; vmcnt loads stay in flight
  };

  for (int hs = 0; hs < NHEMO; ++hs) {
    body(xb0, pb1, true, false);
    body(xb1, pb0, true, false);
    body(xb0, pb1, true, false);
    body(xb1, pb0, true, false);
    body(xb0, pb1, true, false);
    body(xb1, pb0, true, false);
    body(xb0, pb1, true, false);
    body(xb1, pb0, true, false);
    if (hs != NHEMO - 1) {
      body(xb0, pb1, true, false);
      body(xb1, pb0, true, true);
    } else {
      body(xb0, pb1, false, false);
      body(xb1, pb0, false, true);
    }
  }

  // ---- outputs: next_state (N,6,B) then bold (N,B) ----
  if (upd) {
    float* o = out + (size_t)R_o * 6 * NB + b;
    o[0]    = E;
    o[NB]   = I;
    o[2*NB] = ss;
    o[3*NB] = ff;
    o[4*NB] = vv;
    o[5*NB] = qq;
    out[NN*6*NB + R_o*NB + b] =
        20.f*(2.38f*(1.f - qq) + 2.f*(1.f - qq/vv) + 0.48f*(1.f - vv))
        + noise_out[R_o*NB + b];
  }
}

extern "C" void kernel_launch(void* const* d_in, const int* in_sizes, int n_in,
                              void* d_out, int out_size, void* d_ws, size_t ws_size,
                              hipStream_t stream) {
  const float* state     = (const float*)d_in[0];
  // d_in[1] = delays (unused by the reference simulation)
  const float* noise_in  = (const float*)d_in[2];
  const float* noise_out = (const float*)d_in[3];
  const float* sc        = (const float*)d_in[4];
  float* out = (float*)d_out;
  dmf_kernel<<<NB, 768, 0, stream>>>(state, noise_in, noise_out, sc, out);
}